// Round 4
// baseline (449.476 us; speedup 1.0000x reference)
//
#include <hip/hip_runtime.h>

// Trilinear 3D warp: image [1,1,256,256,256] f32, dvf [1,3,256,256,256] f32
// dvf channels: 0=dy, 1=dx, 2=dz. Layout (H,W,D), D innermost.
//
// R1: fused z-pair gather into one float2 load.
// R2: wave-level 3D tiling (wave = 16z x 4x, block = 4y x 4x x 16z).
// R3: bz-fastest schedule + XCD-contiguous chunking + NT dvf loads.
// R4 (this): LDS-staged gather. The limiter is L1 line-request service
// (~230 requests/wave vs 351 cy/wave); per-lane jittered gathers can't
// coalesce (>=45 distinct lines/gather for ANY wave shape). Fix: stage the
// block's image region (tile + +/-4 halo = 13x13x28 f32 = 18.9 KB) in LDS
// with coalesced float4 loads (~74 lines/wave), then gather via ds_read2_b32.
// Corners outside the region (P ~ 2e-4, N(0,1) tail) fall back to the exact
// global float2 path, so results are bit-identical. Border blocks (18%) use
// a scalar-clamped staging path (block-uniform branch). NT store dropped
// (it defeated L2 write-coalescing: WRITE_SIZE 65.5->84.4 MB in R3).

constexpr int H = 256, W = 256, D = 256;
constexpr int N = H * W * D;

constexpr int HALO = 4;
constexpr int RY = 13;              // 4 + 2*4 + 1
constexpr int RX = 13;
constexpr int RZ = 28;              // 16 + 2*4 + pad to 7 float4 chunks
constexpr int NCOL = RY * RX;       // 169 (y,x) columns
constexpr int ITEMS = NCOL * (RZ / 4);  // 1183 float4 staging items

__global__ __launch_bounds__(256) void warp3d_kernel(
    const float* __restrict__ img,
    const float* __restrict__ dvf,
    float* __restrict__ out)
{
    __shared__ float s[RY * RX * RZ];   // 18,928 B -> 8 blocks/CU

    // lane -> (z,x), wave -> y
    const int t  = threadIdx.x;
    const int zt = t & 15;
    const int xt = (t >> 4) & 3;
    const int yt = t >> 6;

    // XCD-contiguous remap, bz fastest (z-halo reuse 1 block away)
    const int orig    = blockIdx.x;
    const int logical = (orig & 7) * 8192 + (orig >> 3);
    const int bz = logical & 15;
    const int bx = (logical >> 4) & 63;
    const int by = logical >> 10;

    const int zb0 = bz << 4;
    const int xb0 = bx << 2;
    const int yb0 = by << 2;

    const int yorg = yb0 - HALO;
    const int xorg = xb0 - HALO;
    const int zorg = zb0 - HALO;

    // dvf loads issued first so HBM latency overlaps the staging loop
    const int z = zb0 + zt;
    const int x = xb0 + xt;
    const int y = yb0 + yt;
    const int i = (y << 16) | (x << 8) | z;

    const float dy = __builtin_nontemporal_load(dvf + i);
    const float dx = __builtin_nontemporal_load(dvf + i + N);
    const float dz = __builtin_nontemporal_load(dvf + i + 2 * N);

    // ---- stage image region into LDS ----
    const bool interior = (yorg >= 0) & (yorg + RY <= H) &
                          (xorg >= 0) & (xorg + RX <= W) &
                          (zorg >= 0) & (zorg + RZ <= D);
    if (interior) {
        const float* base = img + ((yorg * W + xorg) * D + zorg);
        for (int k = t; k < ITEMS; k += 256) {
            const int col = k / 7;          // 0..168
            const int ch  = k - col * 7;    // 0..6
            const int ry  = col / 13;
            const int rx  = col - ry * 13;
            const float4 v = *reinterpret_cast<const float4*>(
                base + (ry * W + rx) * D + ch * 4);   // 16B-aligned (zorg%4==0)
            *reinterpret_cast<float4*>(&s[(ry * RX + rx) * RZ + ch * 4]) = v;
        }
    } else {
        for (int k = t; k < ITEMS; k += 256) {
            const int col = k / 7;
            const int ch  = k - col * 7;
            const int ry  = col / 13;
            const int rx  = col - ry * 13;
            const int cy = min(max(yorg + ry, 0), H - 1);
            const int cx = min(max(xorg + rx, 0), W - 1);
            const int rowb = (cy * W + cx) * D;
            float* dst = &s[(ry * RX + rx) * RZ + ch * 4];
            #pragma unroll
            for (int j = 0; j < 4; ++j) {
                const int cz = min(max(zorg + ch * 4 + j, 0), D - 1);
                dst[j] = img[rowb + cz];
            }
        }
    }
    __syncthreads();

    // ---- per-output trilinear ----
    const float ny = (float)y + dy;
    const float nx = (float)x + dx;
    const float nz = (float)z + dz;

    const int iy = (int)floorf(ny);
    const int ix = (int)floorf(nx);
    const int iz = (int)floorf(nz);

    const int y0 = min(max(iy,     0), H - 1);
    const int y1 = min(max(iy + 1, 0), H - 1);
    const int x0 = min(max(ix,     0), W - 1);
    const int x1 = min(max(ix + 1, 0), W - 1);
    const int z0 = min(max(iz,     0), D - 1);
    const int z1 = min(max(iz + 1, 0), D - 1);

    // fractions use the CLIPPED low corner (matches reference exactly)
    const float yd = ny - (float)y0;
    const float xd = nx - (float)x0;
    const float zd = nz - (float)z0;

    const int zb = min(z0, D - 2);
    const bool lo = (z0 == zb);       // low corner is v.x
    const bool hi = (z1 == zb + 1);   // high corner is v.y

    // region-relative coords + in-region tests (unsigned trick covers <0)
    const int rz  = zb - zorg;
    const int ry0 = y0 - yorg, ry1 = y1 - yorg;
    const int rx0 = x0 - xorg, rx1 = x1 - xorg;
    const bool inz = (unsigned)rz <= (unsigned)(RZ - 2);   // rz+1 <= RZ-1

    float2 v00, v01, v10, v11;

    if (inz & ((unsigned)ry0 < RY) & ((unsigned)rx0 < RX)) {
        const int a = (ry0 * RX + rx0) * RZ + rz;
        v00 = make_float2(s[a], s[a + 1]);                  // ds_read2_b32
    } else {
        v00 = *reinterpret_cast<const float2*>(img + (y0 * W + x0) * D + zb);
    }
    if (inz & ((unsigned)ry0 < RY) & ((unsigned)rx1 < RX)) {
        const int a = (ry0 * RX + rx1) * RZ + rz;
        v01 = make_float2(s[a], s[a + 1]);
    } else {
        v01 = *reinterpret_cast<const float2*>(img + (y0 * W + x1) * D + zb);
    }
    if (inz & ((unsigned)ry1 < RY) & ((unsigned)rx0 < RX)) {
        const int a = (ry1 * RX + rx0) * RZ + rz;
        v10 = make_float2(s[a], s[a + 1]);
    } else {
        v10 = *reinterpret_cast<const float2*>(img + (y1 * W + x0) * D + zb);
    }
    if (inz & ((unsigned)ry1 < RY) & ((unsigned)rx1 < RX)) {
        const int a = (ry1 * RX + rx1) * RZ + rz;
        v11 = make_float2(s[a], s[a + 1]);
    } else {
        v11 = *reinterpret_cast<const float2*>(img + (y1 * W + x1) * D + zb);
    }

    const float c000 = lo ? v00.x : v00.y;
    const float c001 = hi ? v00.y : v00.x;
    const float c010 = lo ? v01.x : v01.y;
    const float c011 = hi ? v01.y : v01.x;
    const float c100 = lo ? v10.x : v10.y;
    const float c101 = hi ? v10.y : v10.x;
    const float c110 = lo ? v11.x : v11.y;
    const float c111 = hi ? v11.y : v11.x;

    const float omz = 1.0f - zd;
    const float c00 = c000 * omz + c001 * zd;
    const float c01 = c010 * omz + c011 * zd;
    const float c10 = c100 * omz + c101 * zd;
    const float c11 = c110 * omz + c111 * zd;

    const float omx = 1.0f - xd;
    const float c0 = c00 * omx + c01 * xd;
    const float c1 = c10 * omx + c11 * xd;

    out[i] = c0 * (1.0f - yd) + c1 * yd;   // plain store: L2 coalesces lines
}

extern "C" void kernel_launch(void* const* d_in, const int* in_sizes, int n_in,
                              void* d_out, int out_size, void* d_ws, size_t ws_size,
                              hipStream_t stream) {
    const float* img = (const float*)d_in[0];
    const float* dvf = (const float*)d_in[1];
    float* out = (float*)d_out;

    dim3 block(256);
    dim3 grid(N / 256);   // 65536 tiles of 4y x 4x x 16z
    warp3d_kernel<<<grid, block, 0, stream>>>(img, dvf, out);
}

// Round 5
// 425.858 us; speedup vs baseline: 1.0555x; 1.0555x over previous
//
#include <hip/hip_runtime.h>

// Trilinear 3D warp: image [1,1,256,256,256] f32, dvf [1,3,256,256,256] f32
// dvf channels: 0=dy, 1=dx, 2=dz. Layout (H,W,D), D innermost.
//
// R1: fused z-pair gather into one float2 load.
// R2: wave-level 3D tiling.  R3: bz-fastest + XCD chunking + NT dvf (150us).
// R4: LDS staging, 4x4x16 tile -> REGRESSED to 208us (VALU 52%: 18.5x staging
//     amplification, 2 magic-divs/item, 4 divergent corner branches).
// R5 (this): LDS staging done lean.
//   - tile 4y x 8x x 16z = 512 outputs, 512 threads: halo amplification 9x.
//   - region 12 x 16 x 24 f32 (18.4 KB), covers jitter in [-4,4) per axis;
//     P(corner outside) ~ 2e-4 -> single in-region test, all-4-corners-LDS
//     (ds_read2) vs all-4-global (exact R3 path). Bit-identical results.
//   - staging decode is shift-only except ONE magic-div by 6:
//     col=k/6, ch=k-6*col, ry=col>>4, rx=col&15; lds = col*24 + 4*ch;
//     gmem off = (ry<<16)+(rx<<8)+(ch<<2). zorg 16B-aligned (zb0%16==0).
//   - 3 block-uniform staging tiers: interior float4 / xy-clamped float4 /
//     z-border scalar.
//   - plain out store (R3 showed NT store inflates WRITE_SIZE 65.5->84MB).

constexpr int H = 256, W = 256, D = 256;
constexpr int N = H * W * D;

constexpr int TY = 4, TX = 8, TZ = 16;      // block tile
constexpr int RY = 12, RX = 16, RZS = 24;   // staged region (f32 units)
constexpr int CH = RZS / 4;                 // 6 float4 chunks per column
constexpr int ITEMS = RY * RX * CH;         // 1152
constexpr int NBLK = N / (TY * TX * TZ);    // 32768

__global__ __launch_bounds__(512) void warp3d_kernel(
    const float* __restrict__ img,
    const float* __restrict__ dvf,
    float* __restrict__ out)
{
    __shared__ float s[RY * RX * RZS];      // 18432 B -> 4 blocks/CU (wave-cap)

    const int t  = threadIdx.x;
    const int zt = t & 15;
    const int xt = (t >> 4) & 7;
    const int yt = t >> 7;

    // XCD-contiguous remap (32768 % 8 == 0, bijective), bz fastest
    const int orig    = blockIdx.x;
    const int logical = (orig & 7) * (NBLK / 8) + (orig >> 3);
    const int bz = logical & 15;
    const int bx = (logical >> 4) & 31;
    const int by = logical >> 9;

    const int zb0 = bz << 4, xb0 = bx << 3, yb0 = by << 2;
    const int yorg = yb0 - 4, xorg = xb0 - 4, zorg = zb0 - 4;

    const int z = zb0 + zt, x = xb0 + xt, y = yb0 + yt;
    const int i = (y << 16) | (x << 8) | z;

    // dvf stream loads first: HBM latency overlaps the staging loop
    const float dy = __builtin_nontemporal_load(dvf + i);
    const float dx = __builtin_nontemporal_load(dvf + i + N);
    const float dz = __builtin_nontemporal_load(dvf + i + 2 * N);

    // ---- stage image region into LDS (3 block-uniform tiers) ----
    const bool zok  = (zorg >= 0) & (zorg + RZS <= D);
    const bool xyok = (yorg >= 0) & (yorg + RY <= H) &
                      (xorg >= 0) & (xorg + RX <= W);
    if (xyok & zok) {                       // ~79.5% of blocks
        const float* base = img + ((yorg * W + xorg) * D + zorg);
        for (int k = t; k < ITEMS; k += 512) {
            const int col = k / CH;         // single magic-div
            const int ch  = k - col * CH;
            const int ry  = col >> 4;
            const int rx  = col & 15;
            const float4 v = *reinterpret_cast<const float4*>(
                base + (ry << 16) + (rx << 8) + (ch << 2));
            *reinterpret_cast<float4*>(&s[col * RZS + (ch << 2)]) = v;
        }
    } else if (zok) {                       // xy-border, z interior (~8%)
        for (int k = t; k < ITEMS; k += 512) {
            const int col = k / CH;
            const int ch  = k - col * CH;
            const int ry  = col >> 4;
            const int rx  = col & 15;
            const int cy = min(max(yorg + ry, 0), H - 1);
            const int cx = min(max(xorg + rx, 0), W - 1);
            const float4 v = *reinterpret_cast<const float4*>(
                img + (((cy << 8) + cx) << 8) + zorg + (ch << 2));
            *reinterpret_cast<float4*>(&s[col * RZS + (ch << 2)]) = v;
        }
    } else {                                // z-border: scalar, z clamped
        for (int k = t; k < ITEMS; k += 512) {
            const int col = k / CH;
            const int ch  = k - col * CH;
            const int ry  = col >> 4;
            const int rx  = col & 15;
            const int cy = min(max(yorg + ry, 0), H - 1);
            const int cx = min(max(xorg + rx, 0), W - 1);
            const int rowb = ((cy << 8) + cx) << 8;
            float* dst = &s[col * RZS + (ch << 2)];
            #pragma unroll
            for (int j = 0; j < 4; ++j) {
                const int cz = min(max(zorg + (ch << 2) + j, 0), D - 1);
                dst[j] = img[rowb + cz];
            }
        }
    }
    __syncthreads();

    // ---- per-output trilinear ----
    const float ny = (float)y + dy;
    const float nx = (float)x + dx;
    const float nz = (float)z + dz;

    const int iy = (int)floorf(ny);
    const int ix = (int)floorf(nx);
    const int iz = (int)floorf(nz);

    const int y0 = min(max(iy,     0), H - 1);
    const int y1 = min(max(iy + 1, 0), H - 1);
    const int x0 = min(max(ix,     0), W - 1);
    const int x1 = min(max(ix + 1, 0), W - 1);
    const int z0 = min(max(iz,     0), D - 1);
    const int z1 = min(max(iz + 1, 0), D - 1);

    // fractions use the CLIPPED low corner (matches reference exactly)
    const float yd = ny - (float)y0;
    const float xd = nx - (float)x0;
    const float zd = nz - (float)z0;

    const int zb = min(z0, D - 2);
    const bool lo = (z0 == zb);       // low corner is .x
    const bool hi = (z1 == zb + 1);   // high corner is .y

    // region-relative clamped coords + single in-region test
    const int ry0 = y0 - yorg, ry1 = y1 - yorg;
    const int rx0 = x0 - xorg, rx1 = x1 - xorg;
    const int rzb = zb - zorg;
    const bool in = (ry0 >= 0) & (ry1 <= RY - 1) &
                    (rx0 >= 0) & (rx1 <= RX - 1) &
                    (rzb >= 0) & (rzb <= RZS - 2);

    float v00x, v00y, v01x, v01y, v10x, v10y, v11x, v11y;
    if (in) {   // ~99.98% of lanes: 4x ds_read2_b32
        const int a00 = ((ry0 << 4) + rx0) * RZS + rzb;
        const int a01 = ((ry0 << 4) + rx1) * RZS + rzb;
        const int a10 = ((ry1 << 4) + rx0) * RZS + rzb;
        const int a11 = ((ry1 << 4) + rx1) * RZS + rzb;
        v00x = s[a00]; v00y = s[a00 + 1];
        v01x = s[a01]; v01y = s[a01 + 1];
        v10x = s[a10]; v10y = s[a10 + 1];
        v11x = s[a11]; v11y = s[a11 + 1];
    } else {    // exact R3 global float2 path
        const float2 v00 = *reinterpret_cast<const float2*>(img + (y0 * W + x0) * D + zb);
        const float2 v01 = *reinterpret_cast<const float2*>(img + (y0 * W + x1) * D + zb);
        const float2 v10 = *reinterpret_cast<const float2*>(img + (y1 * W + x0) * D + zb);
        const float2 v11 = *reinterpret_cast<const float2*>(img + (y1 * W + x1) * D + zb);
        v00x = v00.x; v00y = v00.y; v01x = v01.x; v01y = v01.y;
        v10x = v10.x; v10y = v10.y; v11x = v11.x; v11y = v11.y;
    }

    const float c000 = lo ? v00x : v00y;
    const float c001 = hi ? v00y : v00x;
    const float c010 = lo ? v01x : v01y;
    const float c011 = hi ? v01y : v01x;
    const float c100 = lo ? v10x : v10y;
    const float c101 = hi ? v10y : v10x;
    const float c110 = lo ? v11x : v11y;
    const float c111 = hi ? v11y : v11x;

    const float omz = 1.0f - zd;
    const float c00 = c000 * omz + c001 * zd;
    const float c01 = c010 * omz + c011 * zd;
    const float c10 = c100 * omz + c101 * zd;
    const float c11 = c110 * omz + c111 * zd;

    const float omx = 1.0f - xd;
    const float c0 = c00 * omx + c01 * xd;
    const float c1 = c10 * omx + c11 * xd;

    out[i] = c0 * (1.0f - yd) + c1 * yd;
}

extern "C" void kernel_launch(void* const* d_in, const int* in_sizes, int n_in,
                              void* d_out, int out_size, void* d_ws, size_t ws_size,
                              hipStream_t stream) {
    const float* img = (const float*)d_in[0];
    const float* dvf = (const float*)d_in[1];
    float* out = (float*)d_out;

    dim3 block(512);
    dim3 grid(NBLK);   // 32768 tiles of 4y x 8x x 16z
    warp3d_kernel<<<grid, block, 0, stream>>>(img, dvf, out);
}

// Round 6
// 404.138 us; speedup vs baseline: 1.1122x; 1.0537x over previous
//
#include <hip/hip_runtime.h>

// Trilinear 3D warp: image [1,1,256,256,256] f32, dvf [1,3,256,256,256] f32
// dvf channels: 0=dy, 1=dx, 2=dz. Layout (H,W,D), D innermost.
//
// R1: fused z-pair gather into one float2 load.
// R2: wave-level 3D tiling (wave = 16z x 4x).
// R3: bz-fastest schedule + XCD chunking + NT dvf loads + plain store (150us).
// R4/R5: LDS staging (two variants) -> both REGRESSED (208/186us). Staging
//   amplification + stage->sync->gather serialization loses to direct gather;
//   L1 absorbs the jittered scatter better than modeled. Abandoned.
// R6 (this): R3 pattern + 4-slot ILP. Each thread owns 4 outputs at
//   z + {0,16,32,48}; wave stays 16z x 4x, so EVERY per-slot access has
//   R3-identical coalescing (dvf 4 lines/slot, store 4 lines/slot, gather
//   corners 16-consecutive-z groups). Phase structure: issue all 12 NT dvf
//   loads -> per-slot addr + 16 gathers outstanding -> blend + store.
//   MLP/lane x4 (R3 was latency-bound: 351 cy/wave vs ~230 cy request floor,
//   nothing saturated, occupancy only 5.3 waves/SIMD). Slot z-ranges abut ->
//   slot j+1 re-hits slot j's z-halo lines in L1.

constexpr int H = 256, W = 256, D = 256;
constexpr int N = H * W * D;
constexpr int NBLK = 16384;         // block = 4y x 4x x 64z outputs

__global__ __launch_bounds__(256) void warp3d_kernel(
    const float* __restrict__ img,
    const float* __restrict__ dvf,
    float* __restrict__ out)
{
    const int t  = threadIdx.x;
    const int zt = t & 15;          // 16 z per wave (consecutive)
    const int xt = (t >> 4) & 3;    // 4 x per wave
    const int yt = t >> 6;          // wave id = y within tile

    // XCD-contiguous remap (16384 % 8 == 0, bijective), bz fastest
    const int orig    = blockIdx.x;
    const int logical = (orig & 7) * (NBLK / 8) + (orig >> 3);
    const int bz = logical & 3;           // 4 z-tiles of 64   (fastest)
    const int bx = (logical >> 2) & 63;   // 64 x-tiles
    const int by = logical >> 8;          // 64 y-tiles        (slowest)

    const int z0b = (bz << 6) + zt;       // slot-0 z
    const int x   = (bx << 2) + xt;
    const int y   = (by << 2) + yt;
    const int ibase = (y << 16) | (x << 8) | z0b;   // +16*j stays in z byte

    // ---- phase 1: issue all dvf stream loads (12 outstanding NT loads) ----
    float dyA[4], dxA[4], dzA[4];
#pragma unroll
    for (int j = 0; j < 4; ++j) {
        const int ij = ibase + (j << 4);
        dyA[j] = __builtin_nontemporal_load(dvf + ij);
        dxA[j] = __builtin_nontemporal_load(dvf + ij + N);
        dzA[j] = __builtin_nontemporal_load(dvf + ij + 2 * N);
    }

    // ---- phase 2: per slot, compute corner addresses + issue gathers ----
    float2 v00[4], v01[4], v10[4], v11[4];
    float ydA[4], xdA[4], zdA[4];
    bool  loA[4], hiA[4];
#pragma unroll
    for (int j = 0; j < 4; ++j) {
        const int z = z0b + (j << 4);
        const float ny = (float)y + dyA[j];
        const float nx = (float)x + dxA[j];
        const float nz = (float)z + dzA[j];

        const int iy = (int)floorf(ny);
        const int ix = (int)floorf(nx);
        const int iz = (int)floorf(nz);

        const int y0 = min(max(iy,     0), H - 1);
        const int y1 = min(max(iy + 1, 0), H - 1);
        const int x0 = min(max(ix,     0), W - 1);
        const int x1 = min(max(ix + 1, 0), W - 1);
        const int z0 = min(max(iz,     0), D - 1);
        const int z1 = min(max(iz + 1, 0), D - 1);

        // fractions use the CLIPPED low corner (matches reference exactly)
        ydA[j] = ny - (float)y0;
        xdA[j] = nx - (float)x0;
        zdA[j] = nz - (float)z0;

        const int zb = min(z0, D - 2);
        loA[j] = (z0 == zb);          // low corner is .x
        hiA[j] = (z1 == zb + 1);      // high corner is .y

        const int r00 = (((y0 << 8) + x0) << 8) + zb;
        const int r01 = (((y0 << 8) + x1) << 8) + zb;
        const int r10 = (((y1 << 8) + x0) << 8) + zb;
        const int r11 = (((y1 << 8) + x1) << 8) + zb;

        v00[j] = *reinterpret_cast<const float2*>(img + r00);
        v01[j] = *reinterpret_cast<const float2*>(img + r01);
        v10[j] = *reinterpret_cast<const float2*>(img + r10);
        v11[j] = *reinterpret_cast<const float2*>(img + r11);
    }

    // ---- phase 3: blend + store ----
#pragma unroll
    for (int j = 0; j < 4; ++j) {
        const bool lo = loA[j], hi = hiA[j];
        const float c000 = lo ? v00[j].x : v00[j].y;
        const float c001 = hi ? v00[j].y : v00[j].x;
        const float c010 = lo ? v01[j].x : v01[j].y;
        const float c011 = hi ? v01[j].y : v01[j].x;
        const float c100 = lo ? v10[j].x : v10[j].y;
        const float c101 = hi ? v10[j].y : v10[j].x;
        const float c110 = lo ? v11[j].x : v11[j].y;
        const float c111 = hi ? v11[j].y : v11[j].x;

        const float zd = zdA[j], omz = 1.0f - zd;
        const float c00 = c000 * omz + c001 * zd;
        const float c01 = c010 * omz + c011 * zd;
        const float c10 = c100 * omz + c101 * zd;
        const float c11 = c110 * omz + c111 * zd;

        const float xd = xdA[j], omx = 1.0f - xd;
        const float c0 = c00 * omx + c01 * xd;
        const float c1 = c10 * omx + c11 * xd;

        out[ibase + (j << 4)] = c0 * (1.0f - ydA[j]) + c1 * ydA[j];
    }
}

extern "C" void kernel_launch(void* const* d_in, const int* in_sizes, int n_in,
                              void* d_out, int out_size, void* d_ws, size_t ws_size,
                              hipStream_t stream) {
    const float* img = (const float*)d_in[0];
    const float* dvf = (const float*)d_in[1];
    float* out = (float*)d_out;

    dim3 block(256);
    dim3 grid(NBLK);   // 16384 tiles of 4y x 4x x 64z
    warp3d_kernel<<<grid, block, 0, stream>>>(img, dvf, out);
}

// Round 7
// 383.350 us; speedup vs baseline: 1.1725x; 1.0542x over previous
//
#include <hip/hip_runtime.h>

// Trilinear 3D warp: image [1,1,256,256,256] f32, dvf [1,3,256,256,256] f32
// dvf channels: 0=dy, 1=dx, 2=dz. Layout (H,W,D), D innermost.
//
// R1: fused z-pair gather into one float2 load.
// R2: wave-level 3D tiling (wave = 16z x 4x).
// R3: bz-fastest schedule + XCD chunking + NT dvf loads + plain store: 150us.
// R4/R5: LDS staging -> regressed (208/186us). Staging amplification +
//   stage->sync->gather serialization loses to direct gather via L1.
// R6: 4-slot ILP -> 159us, occupancy 34%. MLP is NOT the limiter.
//   Triangulation: kernel is TA/TCP request-service bound (~950 line-req per
//   4-wave group vs ~1 req/cy); HBM 17%, VALU 20%, nothing else busy.
// R7 (this): exact R3 structure, block 512 (tile 8y x 4x x 16z). Fewer
//   blocks (32768) -> less dispatch overhead, deeper per-CU wave pool,
//   y-halo reuse distance halved. Wave-level access pattern IDENTICAL to R3.

constexpr int H = 256, W = 256, D = 256;
constexpr int N = H * W * D;
constexpr int NBLK = N / 512;       // 32768 tiles of 8y x 4x x 16z

__global__ __launch_bounds__(512) void warp3d_kernel(
    const float* __restrict__ img,
    const float* __restrict__ dvf,
    float* __restrict__ out)
{
    // lane -> (z,x), wave -> y (identical wave shape to R3)
    const int t  = threadIdx.x;
    const int zt = t & 15;          // 16 z per wave
    const int xt = (t >> 4) & 3;    // 4 x per wave
    const int yt = t >> 6;          // wave id = y within tile (0..7)

    // XCD-contiguous remap (32768 % 8 == 0, bijective), bz fastest
    const int orig    = blockIdx.x;
    const int logical = (orig & 7) * (NBLK / 8) + (orig >> 3);
    const int bz = logical & 15;          // 16 z-tiles   (fastest)
    const int bx = (logical >> 4) & 63;   // 64 x-tiles
    const int by = logical >> 10;         // 32 y-tiles   (slowest)

    const int z = (bz << 4) + zt;
    const int x = (bx << 2) + xt;
    const int y = (by << 3) + yt;

    const int i = (y << 16) | (x << 8) | z;   // (y*W + x)*D + z, dims all 256

    // dvf stream loads: single-touch, keep out of cache
    const float dy = __builtin_nontemporal_load(dvf + i);
    const float dx = __builtin_nontemporal_load(dvf + i + N);
    const float dz = __builtin_nontemporal_load(dvf + i + 2 * N);

    const float ny = (float)y + dy;
    const float nx = (float)x + dx;
    const float nz = (float)z + dz;

    const int iy = (int)floorf(ny);
    const int ix = (int)floorf(nx);
    const int iz = (int)floorf(nz);

    const int y0 = min(max(iy,     0), H - 1);
    const int y1 = min(max(iy + 1, 0), H - 1);
    const int x0 = min(max(ix,     0), W - 1);
    const int x1 = min(max(ix + 1, 0), W - 1);
    const int z0 = min(max(iz,     0), D - 1);
    const int z1 = min(max(iz + 1, 0), D - 1);

    // fractions use the CLIPPED low corner (matches reference exactly)
    const float yd = ny - (float)y0;
    const float xd = nx - (float)x0;
    const float zd = nz - (float)z0;

    const int zb = min(z0, D - 2);
    const bool lo = (z0 == zb);       // low corner is v.x
    const bool hi = (z1 == zb + 1);   // high corner is v.y

    const int r00 = (y0 * W + x0) * D + zb;
    const int r01 = (y0 * W + x1) * D + zb;
    const int r10 = (y1 * W + x0) * D + zb;
    const int r11 = (y1 * W + x1) * D + zb;

    // one 8B gather per corner column (4B-aligned; gfx950 handles unaligned)
    const float2 v00 = *reinterpret_cast<const float2*>(img + r00);
    const float2 v01 = *reinterpret_cast<const float2*>(img + r01);
    const float2 v10 = *reinterpret_cast<const float2*>(img + r10);
    const float2 v11 = *reinterpret_cast<const float2*>(img + r11);

    const float c000 = lo ? v00.x : v00.y;
    const float c001 = hi ? v00.y : v00.x;
    const float c010 = lo ? v01.x : v01.y;
    const float c011 = hi ? v01.y : v01.x;
    const float c100 = lo ? v10.x : v10.y;
    const float c101 = hi ? v10.y : v10.x;
    const float c110 = lo ? v11.x : v11.y;
    const float c111 = hi ? v11.y : v11.x;

    const float omz = 1.0f - zd;
    const float c00 = c000 * omz + c001 * zd;
    const float c01 = c010 * omz + c011 * zd;
    const float c10 = c100 * omz + c101 * zd;
    const float c11 = c110 * omz + c111 * zd;

    const float omx = 1.0f - xd;
    const float c0 = c00 * omx + c01 * xd;
    const float c1 = c10 * omx + c11 * xd;

    out[i] = c0 * (1.0f - yd) + c1 * yd;   // plain store: L2 coalesces lines
}

extern "C" void kernel_launch(void* const* d_in, const int* in_sizes, int n_in,
                              void* d_out, int out_size, void* d_ws, size_t ws_size,
                              hipStream_t stream) {
    const float* img = (const float*)d_in[0];
    const float* dvf = (const float*)d_in[1];
    float* out = (float*)d_out;

    dim3 block(512);
    dim3 grid(NBLK);   // 32768 tiles of 8y x 4x x 16z
    warp3d_kernel<<<grid, block, 0, stream>>>(img, dvf, out);
}